// Round 7
// baseline (744.746 us; speedup 1.0000x reference)
//
#include <hip/hip_runtime.h>

// ---------------- types ----------------
typedef short           s16x8 __attribute__((ext_vector_type(8)));
typedef unsigned short  u16;
typedef unsigned short  u16x8 __attribute__((ext_vector_type(8)));
typedef float           f32x4 __attribute__((ext_vector_type(4)));

// ---------------- dims ----------------
#define DB   8192
#define DI   256
#define DH   1024
#define D4H  4096
#define KXH  1280   // I + H
#define NTG  (KXH / 64)   // 20 K-tiles for gates
#define FBLK 512          // f_node fused kernel: 64x8 blocks, 2/CU

// ---------------- helpers ----------------
__device__ __forceinline__ u16 f2bf(float f) {
    unsigned u = __float_as_uint(f);
    u = (u + 0x7FFFu + ((u >> 16) & 1u)) >> 16;
    return (u16)u;
}
__device__ __forceinline__ float bf2f(u16 v) {
    return __uint_as_float(((unsigned)v) << 16);
}
__device__ __forceinline__ float rcp_(float x) { return __builtin_amdgcn_rcpf(x); }
__device__ __forceinline__ float sigmoid_(float x) {
    x = fminf(fmaxf(x, -30.f), 30.f);
    return rcp_(1.0f + __expf(-x));
}
__device__ __forceinline__ float tanh_(float x) {
    x = fminf(fmaxf(x, -15.f), 15.f);
    float e = __expf(2.0f * x);
    return (e - 1.0f) * rcp_(e + 1.0f);
}
__device__ __forceinline__ void gload16(const void* g, void* l) {
    __builtin_amdgcn_global_load_lds(
        (const __attribute__((address_space(1))) unsigned int*)g,
        (__attribute__((address_space(3))) unsigned int*)l, 16, 0, 0);
}
__device__ __forceinline__ void barrier_() {
    asm volatile("" ::: "memory");
    __builtin_amdgcn_s_barrier();
    asm volatile("" ::: "memory");
}

// Grid barrier for the fused f_node kernel. Requires all FBLK blocks resident
// (guaranteed: 32KB LDS + launch_bounds(256,2) -> 2 blocks/CU x 256 CUs).
// Counters zeroed by k_prep_all every call (replay-safe). Device-scope
// atomics per G12/G16; acquire fence invalidates local caches after spin.
__device__ __forceinline__ void gridbar(int* c, int tgt) {
    __threadfence();                      // release this thread's global writes
    __syncthreads();
    if (threadIdx.x == 0) {
        __hip_atomic_fetch_add(c, 1, __ATOMIC_ACQ_REL, __HIP_MEMORY_SCOPE_AGENT);
        while (__hip_atomic_load(c, __ATOMIC_ACQUIRE, __HIP_MEMORY_SCOPE_AGENT) < tgt)
            __builtin_amdgcn_s_sleep(8);
        __builtin_amdgcn_fence(__ATOMIC_ACQUIRE, "agent");
    }
    __syncthreads();
}

// ============================================================================
// 8-phase 256x256 gates GEMM (R5 structure, 108us), fused LSTM activation.
// ============================================================================
__global__ __launch_bounds__(512, 2) void k_gates8(
    const u16* __restrict__ xh, const u16* __restrict__ Wg,
    const float* __restrict__ bsum, const float* __restrict__ cin,
    float* __restrict__ outc, u16* __restrict__ htl)
{
    __shared__ u16 lds[65536];              // 128 KB: [buf][A|B][256*64]

    const int t    = threadIdx.x;
    const int lane = t & 63;
    const int w    = t >> 6;                // 0..7
    const int wm   = w >> 2;                // 0..1
    const int wn   = w & 3;                 // 0..3
    const int l15  = lane & 15;
    const int lg   = lane >> 4;
    const int swz  = l15 & 7;

    const int m0 = blockIdx.x * 256;
    const int n0 = blockIdx.y * 256;

    f32x4 acc[8][4];
    {   f32x4 z4 = {0.f, 0.f, 0.f, 0.f};
#pragma unroll
        for (int i = 0; i < 8; ++i)
#pragma unroll
            for (int j = 0; j < 4; ++j) acc[i][j] = z4;
    }

    const int r0 = t >> 3,        c80 = (t & 7) ^ (r0 & 7);
    const int r1 = (512 + t) >> 3, c81 = (t & 7) ^ (r1 & 7);
    const u16* gA0 = xh + (size_t)(m0 + r0) * KXH + c80 * 8;
    const u16* gA1 = xh + (size_t)(m0 + r1) * KXH + c81 * 8;
    const u16* gB0 = Wg + (size_t)(n0 + r0) * KXH + c80 * 8;
    const u16* gB1 = Wg + (size_t)(n0 + r1) * KXH + c81 * 8;
    u16* lw0 = lds + w * 512;

#define STAGE8(ab, h, tau) do {                                              \
        int tc_ = (tau) < NTG ? (tau) : NTG - 1;                             \
        int bo_ = ((tau) & 1) * 32768 + (ab) * 16384 + (h) * 8192;           \
        const u16* s0_ = ((ab) ? gB0 : gA0) + (size_t)(h) * 128 * KXH + tc_ * 64; \
        const u16* s1_ = ((ab) ? gB1 : gA1) + (size_t)(h) * 128 * KXH + tc_ * 64; \
        gload16(s0_, lw0 + bo_);                                             \
        gload16(s1_, lw0 + bo_ + 4096);                                      \
    } while (0)

    const int uK0  = (lg ^ swz) * 8;
    const int uK1  = ((4 + lg) ^ swz) * 8;
    const int aoff = (wm * 128 + l15) * 64;
    const int boff = (wn * 64 + l15) * 64;

#define RD_A8(a)                                                             \
    _Pragma("unroll") for (int mi = 0; mi < 4; ++mi) {                       \
        const u16* p_ = bufA + aoff + ((a) * 64 + mi * 16) * 64;             \
        av[mi][0] = *(const s16x8*)(p_ + uK0);                               \
        av[mi][1] = *(const s16x8*)(p_ + uK1);                               \
    }
#define RD_B8(b, bvv)                                                        \
    _Pragma("unroll") for (int ni = 0; ni < 2; ++ni) {                       \
        const u16* p_ = bufB + boff + ((b) * 32 + ni * 16) * 64;             \
        bvv[ni][0] = *(const s16x8*)(p_ + uK0);                              \
        bvv[ni][1] = *(const s16x8*)(p_ + uK1);                              \
    }
#define MFMA_Q8(ar, bc, bvv)                                                 \
    __builtin_amdgcn_s_setprio(1);                                           \
    _Pragma("unroll") for (int mi = 0; mi < 4; ++mi)                         \
    _Pragma("unroll") for (int ni = 0; ni < 2; ++ni) {                       \
        acc[(ar) + mi][(bc) + ni] = __builtin_amdgcn_mfma_f32_16x16x32_bf16( \
            av[mi][0], bvv[ni][0], acc[(ar) + mi][(bc) + ni], 0, 0, 0);      \
        acc[(ar) + mi][(bc) + ni] = __builtin_amdgcn_mfma_f32_16x16x32_bf16( \
            av[mi][1], bvv[ni][1], acc[(ar) + mi][(bc) + ni], 0, 0, 0);      \
    }                                                                        \
    __builtin_amdgcn_s_setprio(0);

    // ---- prologue ----
    STAGE8(0, 0, 0); STAGE8(0, 1, 0); STAGE8(1, 0, 0); STAGE8(1, 1, 0);
    STAGE8(1, 0, 1); STAGE8(0, 0, 1);
    asm volatile("s_waitcnt vmcnt(4)" ::: "memory");
    __builtin_amdgcn_s_barrier();
    asm volatile("" ::: "memory");

    // ---- main loop ----
    for (int tt = 0; tt < NTG; ++tt) {
        const u16* bufA = lds + (tt & 1) * 32768;
        const u16* bufB = bufA + 16384;
        s16x8 av[4][2], bv0[2][2], bv1[2][2];
        RD_A8(0); RD_B8(0, bv0);
        STAGE8(0, 1, tt + 1);
        barrier_();
        MFMA_Q8(0, 0, bv0);
        barrier_();
        RD_B8(1, bv1);
        STAGE8(1, 1, tt + 1);
        barrier_();
        MFMA_Q8(0, 2, bv1);
        barrier_();
        RD_A8(1);
        STAGE8(1, 0, tt + 2);
        barrier_();
        MFMA_Q8(4, 0, bv0);
        barrier_();
        STAGE8(0, 0, tt + 2);
        barrier_();
        MFMA_Q8(4, 2, bv1);
        asm volatile("s_waitcnt vmcnt(4)" ::: "memory");
        barrier_();
    }

    // ---- fused LSTM epilogue ----
    const int hb = ((n0 + wn * 64) >> 6) * 16 + l15;
    const int cb = n0 + wn * 64 + l15;
    const float bi = bsum[cb];
    const float bf = bsum[cb + 16];
    const float bg = bsum[cb + 32];
    const float bo = bsum[cb + 48];
#pragma unroll
    for (int mb = 0; mb < 8; ++mb) {
#pragma unroll
        for (int r = 0; r < 4; ++r) {
            const int m = m0 + wm * 128 + mb * 16 + lg * 4 + r;
            const size_t idx = (size_t)m * DH + hb;
            float iv = acc[mb][0][r] + bi;
            float fv = acc[mb][1][r] + bf;
            float gv = acc[mb][2][r] + bg;
            float ov = acc[mb][3][r] + bo;
            float cn = sigmoid_(fv) * cin[idx] + sigmoid_(iv) * tanh_(gv);
            outc[idx] = cn;
            htl[idx] = f2bf(sigmoid_(ov) * tanh_(cn));
        }
        __builtin_amdgcn_sched_barrier(0);
    }
#undef STAGE8
#undef RD_A8
#undef RD_B8
#undef MFMA_Q8
}

// ---------------- m97-structure GEMM core (R1-verified) ------
template<int KTOT, int BM, int BN>
__device__ __forceinline__ void gemm_tile(
    const u16* __restrict__ A, int lda,
    const u16* __restrict__ Bw, int ldb,
    int m0, int n0, u16* As, u16* Bs,
    f32x4 (&acc)[BM / 32][BN / 32])
{
    constexpr int MI = BM / 32, NI = BN / 32;
    const int t    = threadIdx.x;
    const int lane = t & 63;
    const int w    = t >> 6;
    const int wrr  = (w >> 1) * (BM / 2);
    const int wcc  = (w & 1) * (BN / 2);

    const int rr  = t >> 3;
    const int sc8 = (t & 7) ^ (rr & 7);
    const u16* gA = A  + (size_t)(m0 + rr) * lda + sc8 * 8;
    const u16* gB = Bw + (size_t)(n0 + rr) * ldb + sc8 * 8;
    u16* lA = As + w * 512;
    u16* lB = Bs + w * 512;

    const int l15 = lane & 15;
    const int lg  = lane >> 4;
    const int swz = l15 & 7;
    const char* cA = (const char*)As;
    const char* cB = (const char*)Bs;
    const int roA = (wrr + l15) * 128;
    const int roB = (wcc + l15) * 128;
    const int c0  = ((0 + lg) ^ swz) * 16;
    const int c1  = ((4 + lg) ^ swz) * 16;

    for (int kt = 0; kt < KTOT; kt += 64) {
#pragma unroll
        for (int q = 0; q < BM / 32; ++q)
            gload16(gA + (size_t)q * 32 * lda, lA + q * 2048);
#pragma unroll
        for (int q = 0; q < BN / 32; ++q)
            gload16(gB + (size_t)q * 32 * ldb, lB + q * 2048);
        gA += 64; gB += 64;
        __syncthreads();

#pragma unroll
        for (int ks = 0; ks < 2; ++ks) {
            const int cc = ks ? c1 : c0;
            s16x8 av[MI], bv[NI];
#pragma unroll
            for (int mi = 0; mi < MI; ++mi)
                av[mi] = *(const s16x8*)(cA + roA + mi * 2048 + cc);
#pragma unroll
            for (int ni = 0; ni < NI; ++ni)
                bv[ni] = *(const s16x8*)(cB + roB + ni * 2048 + cc);
#pragma unroll
            for (int mi = 0; mi < MI; ++mi)
#pragma unroll
                for (int ni = 0; ni < NI; ++ni)
                    acc[mi][ni] = __builtin_amdgcn_mfma_f32_16x16x32_bf16(
                        av[mi], bv[ni], acc[mi][ni], 0, 0, 0);
        }
        __syncthreads();
    }
}

#define GEMM_PROLOGUE(BM, BN)                                      \
    __shared__ u16 As[(BM) * 64], Bs[(BN) * 64];                   \
    f32x4 acc[(BM) / 32][(BN) / 32];                               \
    {   f32x4 z4 = {0.f, 0.f, 0.f, 0.f};                           \
        _Pragma("unroll") for (int i = 0; i < (BM) / 32; ++i)      \
        _Pragma("unroll") for (int j = 0; j < (BN) / 32; ++j)      \
            acc[i][j] = z4; }                                      \
    const int m0 = blockIdx.x * (BM), n0 = blockIdx.y * (BN);      \
    const int lane = threadIdx.x & 63, w = threadIdx.x >> 6;       \
    const int wrr = (w >> 1) * ((BM) / 2),                         \
              wcc = (w & 1) * ((BN) / 2);                          \
    const int l15 = lane & 15, lg = lane >> 4;

#define ZEROACC()                                                  \
    {   f32x4 z4 = {0.f, 0.f, 0.f, 0.f};                           \
        _Pragma("unroll") for (int i = 0; i < 4; ++i)              \
        _Pragma("unroll") for (int j = 0; j < 4; ++j)              \
            acc[i][j] = z4; }

#define EPILOGUE_LOOP(MI, NI, BODY)                                \
    _Pragma("unroll") for (int mi = 0; mi < (MI); ++mi) {          \
    _Pragma("unroll") for (int ni = 0; ni < (NI); ++ni)            \
    _Pragma("unroll") for (int r = 0; r < 4; ++r) {                \
        const int m = m0 + wrr + mi * 16 + lg * 4 + r;             \
        const int n = n0 + wcc + ni * 16 + l15;                    \
        float v = acc[mi][ni][r];                                  \
        BODY                                                       \
    }                                                              \
    __builtin_amdgcn_sched_barrier(0); }

// ---------------- Wc = W1 @ W2 (small standalone GEMM) ----------------
__global__ __launch_bounds__(256) void k_wc(
    const u16* __restrict__ W1z, const u16* __restrict__ W2t, u16* __restrict__ wc)
{
    GEMM_PROLOGUE(64, 128);
    gemm_tile<DH, 64, 128>(W1z, DH, W2t, DH, m0, n0, As, Bs, acc);
    EPILOGUE_LOOP(2, 4, { wc[(size_t)m * DH + n] = f2bf(v); })
}

// ============================================================================
// Fused f_node chain (R7): 5 GEMM stages in one kernel, grid-barrier synced.
// u = htl@W1^T kept in registers (bf16-packed, identical rounding to R6 ubuf).
//   S1: u = htl@W1z^T ; z1 = tanh(u+b1+t0 wt)          -> z1 global
//   S2: z2 = tanh(u + .5dt(z1@wc^T + v) + b1 + tm wt)  -> z2 global
//   S3: z3 = tanh(u + .5dt(z2@wc^T + v) + b1 + tm wt)  -> z3 global
//   S4: z4 = tanh(u + dt(z3@wc^T + v) + b1 + t1 wt); S = z1+2z2+2z3+z4 -> Sb
//   S5: h  = htl + dt/6 (S@W2b^T + 6 b2)               -> outh
// 512 blocks (64x8 of 128^2 tiles), exactly 2/CU resident -> barrier-safe.
// ============================================================================
__global__ __launch_bounds__(256, 2) void k_fnode(
    const u16* __restrict__ htl, const u16* __restrict__ W1z,
    const u16* __restrict__ wc, const u16* __restrict__ W2b,
    const float* __restrict__ b1, const float* __restrict__ wt,
    const float* __restrict__ vvec, const float* __restrict__ b2,
    const float* __restrict__ t0p, const float* __restrict__ t1p,
    u16* __restrict__ z1, u16* __restrict__ z2, u16* __restrict__ z3,
    u16* __restrict__ Sb, float* __restrict__ outh, int* cnt)
{
    GEMM_PROLOGUE(128, 128);
    u16x8 ureg[8];                     // per-lane u chunk (64 outputs, bf16)

    const float t0v = *t0p, t1v = *t1p;
    const float dtv = t1v - t0v;
    const float tmv = t0v + 0.5f * dtv;

    // ---- S1: u + z1 ----
    gemm_tile<DH, 128, 128>(htl, DH, W1z, DH, m0, n0, As, Bs, acc);
    EPILOGUE_LOOP(4, 4, {
        const int fl = mi * 16 + ni * 4 + r;
        ureg[fl >> 3][fl & 7] = f2bf(v);
        z1[(size_t)m * DH + n] = f2bf(tanh_(v + b1[n] + t0v * wt[n]));
    })
    gridbar(cnt + 0, FBLK);

    // ---- S2 ----
    ZEROACC();
    gemm_tile<DH, 128, 128>(z1, DH, wc, DH, m0, n0, As, Bs, acc);
    EPILOGUE_LOOP(4, 4, {
        const int fl = mi * 16 + ni * 4 + r;
        float u = bf2f(ureg[fl >> 3][fl & 7]);
        float g = u + (0.5f * dtv) * (v + vvec[n]) + b1[n] + tmv * wt[n];
        z2[(size_t)m * DH + n] = f2bf(tanh_(g));
    })
    gridbar(cnt + 1, FBLK);

    // ---- S3 ----
    ZEROACC();
    gemm_tile<DH, 128, 128>(z2, DH, wc, DH, m0, n0, As, Bs, acc);
    EPILOGUE_LOOP(4, 4, {
        const int fl = mi * 16 + ni * 4 + r;
        float u = bf2f(ureg[fl >> 3][fl & 7]);
        float g = u + (0.5f * dtv) * (v + vvec[n]) + b1[n] + tmv * wt[n];
        z3[(size_t)m * DH + n] = f2bf(tanh_(g));
    })
    gridbar(cnt + 2, FBLK);

    // ---- S4: z4 + S ----
    ZEROACC();
    gemm_tile<DH, 128, 128>(z3, DH, wc, DH, m0, n0, As, Bs, acc);
    EPILOGUE_LOOP(4, 4, {
        const int fl = mi * 16 + ni * 4 + r;
        float u = bf2f(ureg[fl >> 3][fl & 7]);
        float z4 = tanh_(u + dtv * (v + vvec[n]) + b1[n] + t1v * wt[n]);
        size_t idx = (size_t)m * DH + n;
        Sb[idx] = f2bf(bf2f(z1[idx]) + 2.f * bf2f(z2[idx])
                       + 2.f * bf2f(z3[idx]) + z4);
    })
    gridbar(cnt + 3, FBLK);

    // ---- S5: h ----
    ZEROACC();
    gemm_tile<DH, 128, 128>(Sb, DH, W2b, DH, m0, n0, As, Bs, acc);
    EPILOGUE_LOOP(4, 4, {
        size_t idx = (size_t)m * DH + n;
        outh[idx] = bf2f(htl[idx]) + (dtv * (1.0f / 6.0f)) * (v + 6.0f * b2[n]);
    })
}

// ---------------- merged prep kernel ----------------
#define NW   (D4H * (KXH / 8))
#define NBS  (D4H / 8)
#define NR1  (DH * (DH / 8))
#define NWT  (DH / 8)
#define NW2  (DH * (DH / 8))
#define NT2  (DH * (DH / 8))
#define NV   (DH)
#define NXH  (DB * (KXH / 8))
#define NZC  8
#define NPREP (NW + NBS + NR1 + NWT + NW2 + NT2 + NV + NXH + NZC)

__global__ __launch_bounds__(256) void k_prep_all(
    const float* __restrict__ x, const float* __restrict__ h,
    const float* __restrict__ Wih, const float* __restrict__ Whh,
    const float* __restrict__ bih, const float* __restrict__ bhh,
    const float* __restrict__ W1, const float* __restrict__ W2,
    const float* __restrict__ b2,
    u16* __restrict__ Wg, float* __restrict__ bsum,
    u16* __restrict__ W1z, float* __restrict__ wt,
    u16* __restrict__ W2b, u16* __restrict__ W2t,
    float* __restrict__ vvec, u16* __restrict__ xh, int* __restrict__ cnt)
{
    int idx = blockIdx.x * 256 + threadIdx.x;
    if (idx < NW) {                                     // gate-interleaved Wg
        int n  = idx / (KXH / 8);
        int k8 = idx - n * (KXH / 8);
        int ro = ((n >> 4) & 3) * DH + (n >> 6) * 16 + (n & 15);
        const float* s = (k8 < DI / 8) ? (Wih + (size_t)ro * DI + k8 * 8)
                                       : (Whh + (size_t)ro * DH + (k8 - DI / 8) * 8);
        f32x4 x0 = *(const f32x4*)s;
        f32x4 x1 = *(const f32x4*)(s + 4);
        u16x8 o;
#pragma unroll
        for (int e = 0; e < 4; ++e) { o[e] = f2bf(x0[e]); o[e + 4] = f2bf(x1[e]); }
        *(u16x8*)(Wg + (size_t)idx * 8) = o;
        return;
    }
    idx -= NW;
    if (idx < NBS) {                                    // permuted combined bias
#pragma unroll
        for (int e = 0; e < 8; ++e) {
            int n = idx * 8 + e;
            int ro = ((n >> 4) & 3) * DH + (n >> 6) * 16 + (n & 15);
            bsum[n] = bih[ro] + bhh[ro];
        }
        return;
    }
    idx -= NBS;
    if (idx < NR1) {                                    // W1 (first DH cols)
        int n = idx >> 7, k8 = idx & 127;
        const float* s = W1 + (size_t)n * (DH + 1) + k8 * 8;  // stride 1025
        u16x8 o;
#pragma unroll
        for (int e = 0; e < 8; ++e) o[e] = f2bf(s[e]);
        *(u16x8*)(W1z + (size_t)idx * 8) = o;
        return;
    }
    idx -= NR1;
    if (idx < NWT) {                                    // W1 time column
#pragma unroll
        for (int e = 0; e < 8; ++e) {
            int n = idx * 8 + e;
            wt[n] = W1[(size_t)n * (DH + 1) + DH];
        }
        return;
    }
    idx -= NWT;
    if (idx < NW2) {                                    // W2 (row-major bf16)
        const float* s = W2 + (size_t)idx * 8;
        f32x4 x0 = *(const f32x4*)s;
        f32x4 x1 = *(const f32x4*)(s + 4);
        u16x8 o;
#pragma unroll
        for (int e = 0; e < 4; ++e) { o[e] = f2bf(x0[e]); o[e + 4] = f2bf(x1[e]); }
        *(u16x8*)(W2b + (size_t)idx * 8) = o;
        return;
    }
    idx -= NW2;
    if (idx < NT2) {                                    // W2t[i][j] = W2[j][i]
        int i = idx >> 7, j8 = (idx & 127) * 8;
        u16x8 o;
#pragma unroll
        for (int e = 0; e < 8; ++e) o[e] = f2bf(W2[(size_t)(j8 + e) * DH + i]);
        *(u16x8*)(W2t + (size_t)i * DH + j8) = o;
        return;
    }
    idx -= NT2;
    if (idx < NV) {                                     // vvec[n] = W1[n,:]·b2
        const float* r = W1 + (size_t)idx * (DH + 1);
        float s = 0.f;
        for (int j = 0; j < DH; ++j) s += r[j] * b2[j];
        vvec[idx] = s;
        return;
    }
    idx -= NV;
    if (idx < NXH) {                                    // xh concat
        int b  = idx / (KXH / 8);
        int k8 = idx - b * (KXH / 8);
        const float* s = (k8 < DI / 8) ? (x + (size_t)b * DI + k8 * 8)
                                       : (h + (size_t)b * DH + (k8 - DI / 8) * 8);
        f32x4 x0 = *(const f32x4*)s;
        f32x4 x1 = *(const f32x4*)(s + 4);
        u16x8 o;
#pragma unroll
        for (int e = 0; e < 4; ++e) { o[e] = f2bf(x0[e]); o[e + 4] = f2bf(x1[e]); }
        *(u16x8*)(xh + (size_t)idx * 8) = o;
        return;
    }
    idx -= NXH;
    if (idx < NZC) cnt[idx] = 0;                        // grid-barrier counters
}

// ---------------- launch ----------------
extern "C" void kernel_launch(void* const* d_in, const int* in_sizes, int n_in,
                              void* d_out, int out_size, void* d_ws, size_t ws_size,
                              hipStream_t stream)
{
    (void)in_sizes; (void)n_in; (void)out_size;
    const float* x_t = (const float*)d_in[0];
    const float* hin = (const float*)d_in[1];
    const float* cin = (const float*)d_in[2];
    const float* t0p = (const float*)d_in[3];
    const float* t1p = (const float*)d_in[4];
    const float* Wih = (const float*)d_in[5];
    const float* Whh = (const float*)d_in[6];
    const float* bih = (const float*)d_in[7];
    const float* bhh = (const float*)d_in[8];
    const float* W1  = (const float*)d_in[9];
    const float* b1  = (const float*)d_in[10];
    const float* W2  = (const float*)d_in[11];
    const float* b2  = (const float*)d_in[12];

    char* ws = (char*)d_ws;
    size_t off = 0;
    u16*   Wg    = (u16*)(ws + off);  off += (size_t)D4H * KXH * 2;  // 10.5 MB
    u16*   W1z   = (u16*)(ws + off);  off += (size_t)DH * DH * 2;
    u16*   W2b   = (u16*)(ws + off);  off += (size_t)DH * DH * 2;
    u16*   W2t   = (u16*)(ws + off);  off += (size_t)DH * DH * 2;
    u16*   wc    = (u16*)(ws + off);  off += (size_t)DH * DH * 2;
    float* wt    = (float*)(ws + off); off += (size_t)DH * 4;
    float* bsum  = (float*)(ws + off); off += (size_t)D4H * 4;
    float* vvec  = (float*)(ws + off); off += (size_t)DH * 4;
    int*   cnt   = (int*)(ws + off);   off += 256;       // barrier counters
    u16*   xh    = (u16*)(ws + off);  off += (size_t)DB * KXH * 2;   // 21.0 MB
    u16*   htl   = (u16*)(ws + off);  off += (size_t)DB * DH * 2;    // 16.8 MB
    u16*   z1    = (u16*)(ws + off);  off += (size_t)DB * DH * 2;
    u16*   z2    = (u16*)(ws + off);  off += (size_t)DB * DH * 2;
    u16*   z3    = (u16*)(ws + off);  off += (size_t)DB * DH * 2;
    u16*   Sb    = (u16*)(ws + off);  off += (size_t)DB * DH * 2;
    if (ws_size < off) return;  // insufficient workspace: fail validation cleanly

    float* outh = (float*)d_out;
    float* outc = outh + (size_t)DB * DH;

    k_prep_all<<<(NPREP + 255) / 256, 256, 0, stream>>>(
        x_t, hin, Wih, Whh, bih, bhh, W1, W2, b2,
        Wg, bsum, W1z, wt, W2b, W2t, vvec, xh, cnt);

    k_wc<<<dim3(DH / 64, DH / 128), 256, 0, stream>>>(W1z, W2t, wc);

    k_gates8<<<dim3(DB / 256, D4H / 256), 512, 0, stream>>>(
        xh, Wg, bsum, cin, outc, htl);

    k_fnode<<<dim3(DB / 128, DH / 128), 256, 0, stream>>>(
        htl, W1z, wc, W2b, b1, wt, vvec, b2, t0p, t1p,
        z1, z2, z3, Sb, outh, cnt);
}

// Round 8
// 296.927 us; speedup vs baseline: 2.5082x; 2.5082x over previous
//
#include <hip/hip_runtime.h>

// ---------------- types ----------------
typedef short           s16x8 __attribute__((ext_vector_type(8)));
typedef unsigned short  u16;
typedef unsigned short  u16x8 __attribute__((ext_vector_type(8)));
typedef float           f32x4 __attribute__((ext_vector_type(4)));

// ---------------- dims ----------------
#define DB   8192
#define DI   256
#define DH   1024
#define D4H  4096
#define KXH  1280   // I + H
#define NTG  (KXH / 64)   // 20 K-tiles for gates

// ---------------- helpers ----------------
__device__ __forceinline__ u16 f2bf(float f) {
    unsigned u = __float_as_uint(f);
    u = (u + 0x7FFFu + ((u >> 16) & 1u)) >> 16;
    return (u16)u;
}
__device__ __forceinline__ float bf2f(u16 v) {
    return __uint_as_float(((unsigned)v) << 16);
}
__device__ __forceinline__ float rcp_(float x) { return __builtin_amdgcn_rcpf(x); }
__device__ __forceinline__ float sigmoid_(float x) {
    x = fminf(fmaxf(x, -30.f), 30.f);
    return rcp_(1.0f + __expf(-x));
}
__device__ __forceinline__ float tanh_(float x) {
    x = fminf(fmaxf(x, -15.f), 15.f);
    float e = __expf(2.0f * x);
    return (e - 1.0f) * rcp_(e + 1.0f);
}
__device__ __forceinline__ void gload16(const void* g, void* l) {
    __builtin_amdgcn_global_load_lds(
        (const __attribute__((address_space(1))) unsigned int*)g,
        (__attribute__((address_space(3))) unsigned int*)l, 16, 0, 0);
}
__device__ __forceinline__ void barrier_() {
    asm volatile("" ::: "memory");
    __builtin_amdgcn_s_barrier();
    asm volatile("" ::: "memory");
}

// ============================================================================
// 8-phase 256x256 gates GEMM (R5 structure, 108us), fused LSTM activation.
// R7 lesson: do NOT grid-sync-fuse producer/consumer GEMMs (XCD L2 flushes).
// ============================================================================
__global__ __launch_bounds__(512, 2) void k_gates8(
    const u16* __restrict__ xh, const u16* __restrict__ Wg,
    const float* __restrict__ bsum, const float* __restrict__ cin,
    float* __restrict__ outc, u16* __restrict__ htl)
{
    __shared__ u16 lds[65536];              // 128 KB: [buf][A|B][256*64]

    const int t    = threadIdx.x;
    const int lane = t & 63;
    const int w    = t >> 6;                // 0..7
    const int wm   = w >> 2;                // 0..1
    const int wn   = w & 3;                 // 0..3
    const int l15  = lane & 15;
    const int lg   = lane >> 4;
    const int swz  = l15 & 7;

    const int m0 = blockIdx.x * 256;
    const int n0 = blockIdx.y * 256;

    f32x4 acc[8][4];
    {   f32x4 z4 = {0.f, 0.f, 0.f, 0.f};
#pragma unroll
        for (int i = 0; i < 8; ++i)
#pragma unroll
            for (int j = 0; j < 4; ++j) acc[i][j] = z4;
    }

    const int r0 = t >> 3,        c80 = (t & 7) ^ (r0 & 7);
    const int r1 = (512 + t) >> 3, c81 = (t & 7) ^ (r1 & 7);
    const u16* gA0 = xh + (size_t)(m0 + r0) * KXH + c80 * 8;
    const u16* gA1 = xh + (size_t)(m0 + r1) * KXH + c81 * 8;
    const u16* gB0 = Wg + (size_t)(n0 + r0) * KXH + c80 * 8;
    const u16* gB1 = Wg + (size_t)(n0 + r1) * KXH + c81 * 8;
    u16* lw0 = lds + w * 512;

#define STAGE8(ab, h, tau) do {                                              \
        int tc_ = (tau) < NTG ? (tau) : NTG - 1;                             \
        int bo_ = ((tau) & 1) * 32768 + (ab) * 16384 + (h) * 8192;           \
        const u16* s0_ = ((ab) ? gB0 : gA0) + (size_t)(h) * 128 * KXH + tc_ * 64; \
        const u16* s1_ = ((ab) ? gB1 : gA1) + (size_t)(h) * 128 * KXH + tc_ * 64; \
        gload16(s0_, lw0 + bo_);                                             \
        gload16(s1_, lw0 + bo_ + 4096);                                      \
    } while (0)

    const int uK0  = (lg ^ swz) * 8;
    const int uK1  = ((4 + lg) ^ swz) * 8;
    const int aoff = (wm * 128 + l15) * 64;
    const int boff = (wn * 64 + l15) * 64;

#define RD_A8(a)                                                             \
    _Pragma("unroll") for (int mi = 0; mi < 4; ++mi) {                       \
        const u16* p_ = bufA + aoff + ((a) * 64 + mi * 16) * 64;             \
        av[mi][0] = *(const s16x8*)(p_ + uK0);                               \
        av[mi][1] = *(const s16x8*)(p_ + uK1);                               \
    }
#define RD_B8(b, bvv)                                                        \
    _Pragma("unroll") for (int ni = 0; ni < 2; ++ni) {                       \
        const u16* p_ = bufB + boff + ((b) * 32 + ni * 16) * 64;             \
        bvv[ni][0] = *(const s16x8*)(p_ + uK0);                              \
        bvv[ni][1] = *(const s16x8*)(p_ + uK1);                              \
    }
#define MFMA_Q8(ar, bc, bvv)                                                 \
    __builtin_amdgcn_s_setprio(1);                                           \
    _Pragma("unroll") for (int mi = 0; mi < 4; ++mi)                         \
    _Pragma("unroll") for (int ni = 0; ni < 2; ++ni) {                       \
        acc[(ar) + mi][(bc) + ni] = __builtin_amdgcn_mfma_f32_16x16x32_bf16( \
            av[mi][0], bvv[ni][0], acc[(ar) + mi][(bc) + ni], 0, 0, 0);      \
        acc[(ar) + mi][(bc) + ni] = __builtin_amdgcn_mfma_f32_16x16x32_bf16( \
            av[mi][1], bvv[ni][1], acc[(ar) + mi][(bc) + ni], 0, 0, 0);      \
    }                                                                        \
    __builtin_amdgcn_s_setprio(0);

    // ---- prologue ----
    STAGE8(0, 0, 0); STAGE8(0, 1, 0); STAGE8(1, 0, 0); STAGE8(1, 1, 0);
    STAGE8(1, 0, 1); STAGE8(0, 0, 1);
    asm volatile("s_waitcnt vmcnt(4)" ::: "memory");
    __builtin_amdgcn_s_barrier();
    asm volatile("" ::: "memory");

    // ---- main loop ----
    for (int tt = 0; tt < NTG; ++tt) {
        const u16* bufA = lds + (tt & 1) * 32768;
        const u16* bufB = bufA + 16384;
        s16x8 av[4][2], bv0[2][2], bv1[2][2];
        RD_A8(0); RD_B8(0, bv0);
        STAGE8(0, 1, tt + 1);
        barrier_();
        MFMA_Q8(0, 0, bv0);
        barrier_();
        RD_B8(1, bv1);
        STAGE8(1, 1, tt + 1);
        barrier_();
        MFMA_Q8(0, 2, bv1);
        barrier_();
        RD_A8(1);
        STAGE8(1, 0, tt + 2);
        barrier_();
        MFMA_Q8(4, 0, bv0);
        barrier_();
        STAGE8(0, 0, tt + 2);
        barrier_();
        MFMA_Q8(4, 2, bv1);
        asm volatile("s_waitcnt vmcnt(4)" ::: "memory");
        barrier_();
    }

    // ---- fused LSTM epilogue ----
    const int hb = ((n0 + wn * 64) >> 6) * 16 + l15;
    const int cb = n0 + wn * 64 + l15;
    const float bi = bsum[cb];
    const float bf = bsum[cb + 16];
    const float bg = bsum[cb + 32];
    const float bo = bsum[cb + 48];
#pragma unroll
    for (int mb = 0; mb < 8; ++mb) {
#pragma unroll
        for (int r = 0; r < 4; ++r) {
            const int m = m0 + wm * 128 + mb * 16 + lg * 4 + r;
            const size_t idx = (size_t)m * DH + hb;
            float iv = acc[mb][0][r] + bi;
            float fv = acc[mb][1][r] + bf;
            float gv = acc[mb][2][r] + bg;
            float ov = acc[mb][3][r] + bo;
            float cn = sigmoid_(fv) * cin[idx] + sigmoid_(iv) * tanh_(gv);
            outc[idx] = cn;
            htl[idx] = f2bf(sigmoid_(ov) * tanh_(cn));
        }
        __builtin_amdgcn_sched_barrier(0);
    }
#undef STAGE8
#undef RD_A8
#undef RD_B8
#undef MFMA_Q8
}

// ---------------- m97-structure GEMM core (R1-verified) ------
template<int KTOT, int BM, int BN>
__device__ __forceinline__ void gemm_tile(
    const u16* __restrict__ A, int lda,
    const u16* __restrict__ Bw, int ldb,
    int m0, int n0, u16* As, u16* Bs,
    f32x4 (&acc)[BM / 32][BN / 32])
{
    constexpr int MI = BM / 32, NI = BN / 32;
    const int t    = threadIdx.x;
    const int lane = t & 63;
    const int w    = t >> 6;
    const int wrr  = (w >> 1) * (BM / 2);
    const int wcc  = (w & 1) * (BN / 2);

    const int rr  = t >> 3;
    const int sc8 = (t & 7) ^ (rr & 7);
    const u16* gA = A  + (size_t)(m0 + rr) * lda + sc8 * 8;
    const u16* gB = Bw + (size_t)(n0 + rr) * ldb + sc8 * 8;
    u16* lA = As + w * 512;
    u16* lB = Bs + w * 512;

    const int l15 = lane & 15;
    const int lg  = lane >> 4;
    const int swz = l15 & 7;
    const char* cA = (const char*)As;
    const char* cB = (const char*)Bs;
    const int roA = (wrr + l15) * 128;
    const int roB = (wcc + l15) * 128;
    const int c0  = ((0 + lg) ^ swz) * 16;
    const int c1  = ((4 + lg) ^ swz) * 16;

    for (int kt = 0; kt < KTOT; kt += 64) {
#pragma unroll
        for (int q = 0; q < BM / 32; ++q)
            gload16(gA + (size_t)q * 32 * lda, lA + q * 2048);
#pragma unroll
        for (int q = 0; q < BN / 32; ++q)
            gload16(gB + (size_t)q * 32 * ldb, lB + q * 2048);
        gA += 64; gB += 64;
        __syncthreads();

#pragma unroll
        for (int ks = 0; ks < 2; ++ks) {
            const int cc = ks ? c1 : c0;
            s16x8 av[MI], bv[NI];
#pragma unroll
            for (int mi = 0; mi < MI; ++mi)
                av[mi] = *(const s16x8*)(cA + roA + mi * 2048 + cc);
#pragma unroll
            for (int ni = 0; ni < NI; ++ni)
                bv[ni] = *(const s16x8*)(cB + roB + ni * 2048 + cc);
#pragma unroll
            for (int mi = 0; mi < MI; ++mi)
#pragma unroll
                for (int ni = 0; ni < NI; ++ni)
                    acc[mi][ni] = __builtin_amdgcn_mfma_f32_16x16x32_bf16(
                        av[mi], bv[ni], acc[mi][ni], 0, 0, 0);
        }
        __syncthreads();
    }
}

#define GEMM_PROLOGUE(BM, BN)                                      \
    __shared__ u16 As[(BM) * 64], Bs[(BN) * 64];                   \
    f32x4 acc[(BM) / 32][(BN) / 32];                               \
    {   f32x4 z4 = {0.f, 0.f, 0.f, 0.f};                           \
        _Pragma("unroll") for (int i = 0; i < (BM) / 32; ++i)      \
        _Pragma("unroll") for (int j = 0; j < (BN) / 32; ++j)      \
            acc[i][j] = z4; }                                      \
    const int m0 = blockIdx.x * (BM), n0 = blockIdx.y * (BN);      \
    const int lane = threadIdx.x & 63, w = threadIdx.x >> 6;       \
    const int wrr = (w >> 1) * ((BM) / 2),                         \
              wcc = (w & 1) * ((BN) / 2);                          \
    const int l15 = lane & 15, lg = lane >> 4;

#define EPILOGUE_LOOP(MI, NI, BODY)                                \
    _Pragma("unroll") for (int mi = 0; mi < (MI); ++mi) {          \
    _Pragma("unroll") for (int ni = 0; ni < (NI); ++ni)            \
    _Pragma("unroll") for (int r = 0; r < 4; ++r) {                \
        const int m = m0 + wrr + mi * 16 + lg * 4 + r;             \
        const int n = n0 + wcc + ni * 16 + l15;                    \
        float v = acc[mi][ni][r];                                  \
        BODY                                                       \
    }                                                              \
    __builtin_amdgcn_sched_barrier(0); }

// ---------------- Wc = W1 @ W2 (small standalone GEMM) ----------------
__global__ __launch_bounds__(256) void k_wc(
    const u16* __restrict__ W1z, const u16* __restrict__ W2t, u16* __restrict__ wc)
{
    GEMM_PROLOGUE(64, 128);
    gemm_tile<DH, 64, 128>(W1z, DH, W2t, DH, m0, n0, As, Bs, acc);
    EPILOGUE_LOOP(2, 4, { wc[(size_t)m * DH + n] = f2bf(v); })
}

// ---------------- f_node: algebraic RK4 (R6 flow, 128^2 tiles) ----------------
// u = htl@W1^T ; cvA = b1+t0*wt ; cvB = .5dt*vvec+b1+tm*wt ; cvC = dt*vvec+b1+t1*wt
// z1 = tanh(u + cvA)
// z2 = tanh(u + .5dt*(z1@wc^T) + cvB) ; z3 same on z2
// z4 = tanh(u + dt*(z3@wc^T) + cvC) ; S = z1+2z2+2z3+z4
// h  = htl + dt/6 * (S@W2^T + 6*b2)

__global__ __launch_bounds__(256) void k_gemm_u(
    const u16* __restrict__ htl, const u16* __restrict__ W1z,
    const float* __restrict__ cvA,
    u16* __restrict__ ubuf, u16* __restrict__ z1)
{
    GEMM_PROLOGUE(128, 128);
    gemm_tile<DH, 128, 128>(htl, DH, W1z, DH, m0, n0, As, Bs, acc);
    EPILOGUE_LOOP(4, 4, {
        size_t idx = (size_t)m * DH + n;
        ubuf[idx] = f2bf(v);
        z1[idx] = f2bf(tanh_(v + cvA[n]));
    })
}

template<int IS4>
__global__ __launch_bounds__(256) void k_gemm_s(
    const u16* __restrict__ zin, const u16* __restrict__ wc,
    const u16* __restrict__ ubuf, const float* __restrict__ cv,
    const float* __restrict__ t0p, const float* __restrict__ t1p, float alpha,
    u16* __restrict__ zout,
    const u16* __restrict__ z1, const u16* __restrict__ z2,
    u16* __restrict__ Sb)
{
    GEMM_PROLOGUE(128, 128);
    gemm_tile<DH, 128, 128>(zin, DH, wc, DH, m0, n0, As, Bs, acc);
    const float ad = alpha * (*t1p - *t0p);
    EPILOGUE_LOOP(4, 4, {
        size_t idx = (size_t)m * DH + n;
        float zz = tanh_(bf2f(ubuf[idx]) + ad * v + cv[n]);
        if (IS4) {
            Sb[idx] = f2bf(bf2f(z1[idx]) + 2.f * bf2f(z2[idx])
                           + 2.f * bf2f(zin[idx]) + zz);
        } else {
            zout[idx] = f2bf(zz);
        }
    })
}

__global__ __launch_bounds__(256) void k_gemm_h(
    const u16* __restrict__ Sb, const u16* __restrict__ W2b,
    const float* __restrict__ b2, const u16* __restrict__ htl,
    const float* __restrict__ t0p, const float* __restrict__ t1p,
    float* __restrict__ outh)
{
    GEMM_PROLOGUE(128, 128);
    gemm_tile<DH, 128, 128>(Sb, DH, W2b, DH, m0, n0, As, Bs, acc);
    const float dtv = *t1p - *t0p;
    EPILOGUE_LOOP(4, 4, {
        size_t idx = (size_t)m * DH + n;
        outh[idx] = bf2f(htl[idx]) + (dtv * (1.0f / 6.0f)) * (v + 6.0f * b2[n]);
    })
}

// ---------------- merged prep kernel ----------------
#define NW   (D4H * (KXH / 8))
#define NBS  (D4H / 8)
#define NR1  (DH * (DH / 8))
#define NW2  (DH * (DH / 8))
#define NT2  (DH * (DH / 8))
#define NCV  (DH)
#define NXH  (DB * (KXH / 8))
#define NPREP (NW + NBS + NR1 + NW2 + NT2 + NCV + NXH)

__global__ __launch_bounds__(256) void k_prep_all(
    const float* __restrict__ x, const float* __restrict__ h,
    const float* __restrict__ Wih, const float* __restrict__ Whh,
    const float* __restrict__ bih, const float* __restrict__ bhh,
    const float* __restrict__ W1, const float* __restrict__ b1,
    const float* __restrict__ W2, const float* __restrict__ b2,
    const float* __restrict__ t0p, const float* __restrict__ t1p,
    u16* __restrict__ Wg, float* __restrict__ bsum,
    u16* __restrict__ W1z, u16* __restrict__ W2b, u16* __restrict__ W2t,
    float* __restrict__ cvA, float* __restrict__ cvB, float* __restrict__ cvC,
    u16* __restrict__ xh)
{
    int idx = blockIdx.x * 256 + threadIdx.x;
    if (idx < NW) {                                     // gate-interleaved Wg
        int n  = idx / (KXH / 8);
        int k8 = idx - n * (KXH / 8);
        int ro = ((n >> 4) & 3) * DH + (n >> 6) * 16 + (n & 15);
        const float* s = (k8 < DI / 8) ? (Wih + (size_t)ro * DI + k8 * 8)
                                       : (Whh + (size_t)ro * DH + (k8 - DI / 8) * 8);
        f32x4 x0 = *(const f32x4*)s;
        f32x4 x1 = *(const f32x4*)(s + 4);
        u16x8 o;
#pragma unroll
        for (int e = 0; e < 4; ++e) { o[e] = f2bf(x0[e]); o[e + 4] = f2bf(x1[e]); }
        *(u16x8*)(Wg + (size_t)idx * 8) = o;
        return;
    }
    idx -= NW;
    if (idx < NBS) {                                    // permuted combined bias
#pragma unroll
        for (int e = 0; e < 8; ++e) {
            int n = idx * 8 + e;
            int ro = ((n >> 4) & 3) * DH + (n >> 6) * 16 + (n & 15);
            bsum[n] = bih[ro] + bhh[ro];
        }
        return;
    }
    idx -= NBS;
    if (idx < NR1) {                                    // W1 (first DH cols)
        int n = idx >> 7, k8 = idx & 127;
        const float* s = W1 + (size_t)n * (DH + 1) + k8 * 8;  // stride 1025
        u16x8 o;
#pragma unroll
        for (int e = 0; e < 8; ++e) o[e] = f2bf(s[e]);
        *(u16x8*)(W1z + (size_t)idx * 8) = o;
        return;
    }
    idx -= NR1;
    if (idx < NW2) {                                    // W2 (row-major bf16)
        const float* s = W2 + (size_t)idx * 8;
        f32x4 x0 = *(const f32x4*)s;
        f32x4 x1 = *(const f32x4*)(s + 4);
        u16x8 o;
#pragma unroll
        for (int e = 0; e < 4; ++e) { o[e] = f2bf(x0[e]); o[e + 4] = f2bf(x1[e]); }
        *(u16x8*)(W2b + (size_t)idx * 8) = o;
        return;
    }
    idx -= NW2;
    if (idx < NT2) {                                    // W2t[i][j] = W2[j][i]
        int i = idx >> 7, j8 = (idx & 127) * 8;
        u16x8 o;
#pragma unroll
        for (int e = 0; e < 8; ++e) o[e] = f2bf(W2[(size_t)(j8 + e) * DH + i]);
        *(u16x8*)(W2t + (size_t)i * DH + j8) = o;
        return;
    }
    idx -= NT2;
    if (idx < NCV) {                                    // per-n RK4 constants
        const float* r = W1 + (size_t)idx * (DH + 1);
        float s = 0.f;
        for (int j = 0; j < DH; ++j) s += r[j] * b2[j];  // vvec[n]
        const float t0v = *t0p, t1v = *t1p;
        const float dtv = t1v - t0v, tmv = t0v + 0.5f * dtv;
        const float wtn = r[DH];                         // W1 time column
        const float b1n = b1[idx];
        cvA[idx] = b1n + t0v * wtn;
        cvB[idx] = 0.5f * dtv * s + b1n + tmv * wtn;
        cvC[idx] = dtv * s + b1n + t1v * wtn;
        return;
    }
    idx -= NCV;
    if (idx < NXH) {                                    // xh concat
        int b  = idx / (KXH / 8);
        int k8 = idx - b * (KXH / 8);
        const float* s = (k8 < DI / 8) ? (x + (size_t)b * DI + k8 * 8)
                                       : (h + (size_t)b * DH + (k8 - DI / 8) * 8);
        f32x4 x0 = *(const f32x4*)s;
        f32x4 x1 = *(const f32x4*)(s + 4);
        u16x8 o;
#pragma unroll
        for (int e = 0; e < 4; ++e) { o[e] = f2bf(x0[e]); o[e + 4] = f2bf(x1[e]); }
        *(u16x8*)(xh + (size_t)idx * 8) = o;
    }
}

// ---------------- launch ----------------
extern "C" void kernel_launch(void* const* d_in, const int* in_sizes, int n_in,
                              void* d_out, int out_size, void* d_ws, size_t ws_size,
                              hipStream_t stream)
{
    (void)in_sizes; (void)n_in; (void)out_size;
    const float* x_t = (const float*)d_in[0];
    const float* hin = (const float*)d_in[1];
    const float* cin = (const float*)d_in[2];
    const float* t0p = (const float*)d_in[3];
    const float* t1p = (const float*)d_in[4];
    const float* Wih = (const float*)d_in[5];
    const float* Whh = (const float*)d_in[6];
    const float* bih = (const float*)d_in[7];
    const float* bhh = (const float*)d_in[8];
    const float* W1  = (const float*)d_in[9];
    const float* b1  = (const float*)d_in[10];
    const float* W2  = (const float*)d_in[11];
    const float* b2  = (const float*)d_in[12];

    char* ws = (char*)d_ws;
    size_t off = 0;
    u16*   Wg    = (u16*)(ws + off);  off += (size_t)D4H * KXH * 2;  // 10.5 MB
    u16*   W1z   = (u16*)(ws + off);  off += (size_t)DH * DH * 2;
    u16*   W2b   = (u16*)(ws + off);  off += (size_t)DH * DH * 2;
    u16*   W2t   = (u16*)(ws + off);  off += (size_t)DH * DH * 2;
    u16*   wc    = (u16*)(ws + off);  off += (size_t)DH * DH * 2;
    float* bsum  = (float*)(ws + off); off += (size_t)D4H * 4;
    float* cvA   = (float*)(ws + off); off += (size_t)DH * 4;
    float* cvB   = (float*)(ws + off); off += (size_t)DH * 4;
    float* cvC   = (float*)(ws + off); off += (size_t)DH * 4;
    u16*   xh    = (u16*)(ws + off);  off += (size_t)DB * KXH * 2;   // 21.0 MB
    u16*   htl   = (u16*)(ws + off);  off += (size_t)DB * DH * 2;    // 16.8 MB
    u16*   ubuf  = (u16*)(ws + off);  off += (size_t)DB * DH * 2;
    u16*   z1    = (u16*)(ws + off);  off += (size_t)DB * DH * 2;
    u16*   z2    = (u16*)(ws + off);  off += (size_t)DB * DH * 2;
    u16*   z3    = (u16*)(ws + off);  off += (size_t)DB * DH * 2;
    u16*   Sb    = (u16*)(ws + off);  off += (size_t)DB * DH * 2;
    if (ws_size < off) return;  // insufficient workspace: fail validation cleanly

    float* outh = (float*)d_out;
    float* outc = outh + (size_t)DB * DH;

    k_prep_all<<<(NPREP + 255) / 256, 256, 0, stream>>>(
        x_t, hin, Wih, Whh, bih, bhh, W1, b1, W2, b2, t0p, t1p,
        Wg, bsum, W1z, W2b, W2t, cvA, cvB, cvC, xh);

    k_wc<<<dim3(DH / 64, DH / 128), 256, 0, stream>>>(W1z, W2t, wc);

    k_gates8<<<dim3(DB / 256, D4H / 256), 512, 0, stream>>>(
        xh, Wg, bsum, cin, outc, htl);

    dim3 gf(DB / 128, DH / 128);
    k_gemm_u<<<gf, 256, 0, stream>>>(htl, W1z, cvA, ubuf, z1);
    k_gemm_s<0><<<gf, 256, 0, stream>>>(z1, wc, ubuf, cvB, t0p, t1p, 0.5f,
                                        z2, nullptr, nullptr, nullptr);
    k_gemm_s<0><<<gf, 256, 0, stream>>>(z2, wc, ubuf, cvB, t0p, t1p, 0.5f,
                                        z3, nullptr, nullptr, nullptr);
    k_gemm_s<1><<<gf, 256, 0, stream>>>(z3, wc, ubuf, cvC, t0p, t1p, 1.0f,
                                        nullptr, z1, z2, Sb);
    k_gemm_h<<<gf, 256, 0, stream>>>(Sb, W2b, b2, htl, t0p, t1p, outh);
}

// Round 9
// 271.218 us; speedup vs baseline: 2.7459x; 1.0948x over previous
//
#include <hip/hip_runtime.h>

// ---------------- types ----------------
typedef short           s16x8 __attribute__((ext_vector_type(8)));
typedef unsigned short  u16;
typedef unsigned short  u16x8 __attribute__((ext_vector_type(8)));
typedef float           f32x4 __attribute__((ext_vector_type(4)));

// ---------------- dims ----------------
#define DB   8192
#define DI   256
#define DH   1024
#define D4H  4096
#define KXH  1280   // I + H
#define NTG  (KXH / 64)   // 20 K-tiles for gates

// ---------------- helpers ----------------
__device__ __forceinline__ u16 f2bf(float f) {
    unsigned u = __float_as_uint(f);
    u = (u + 0x7FFFu + ((u >> 16) & 1u)) >> 16;
    return (u16)u;
}
__device__ __forceinline__ float bf2f(u16 v) {
    return __uint_as_float(((unsigned)v) << 16);
}
__device__ __forceinline__ float rcp_(float x) { return __builtin_amdgcn_rcpf(x); }
__device__ __forceinline__ float sigmoid_(float x) {
    x = fminf(fmaxf(x, -30.f), 30.f);
    return rcp_(1.0f + __expf(-x));
}
__device__ __forceinline__ float tanh_(float x) {
    x = fminf(fmaxf(x, -15.f), 15.f);
    float e = __expf(2.0f * x);
    return (e - 1.0f) * rcp_(e + 1.0f);
}
__device__ __forceinline__ void gload16(const void* g, void* l) {
    __builtin_amdgcn_global_load_lds(
        (const __attribute__((address_space(1))) unsigned int*)g,
        (__attribute__((address_space(3))) unsigned int*)l, 16, 0, 0);
}
__device__ __forceinline__ void barrier_() {
    asm volatile("" ::: "memory");
    __builtin_amdgcn_s_barrier();
    asm volatile("" ::: "memory");
}

// ============================================================================
// 8-phase 256x256 gates GEMM (R5 structure, ~108us), fused LSTM activation.
// R7 lesson: do NOT grid-sync-fuse producer/consumer GEMMs (XCD L2 flushes).
// ============================================================================
__global__ __launch_bounds__(512, 2) void k_gates8(
    const u16* __restrict__ xh, const u16* __restrict__ Wg,
    const float* __restrict__ bsum, const float* __restrict__ cin,
    float* __restrict__ outc, u16* __restrict__ htl)
{
    __shared__ u16 lds[65536];              // 128 KB: [buf][A|B][256*64]

    const int t    = threadIdx.x;
    const int lane = t & 63;
    const int w    = t >> 6;                // 0..7
    const int wm   = w >> 2;                // 0..1
    const int wn   = w & 3;                 // 0..3
    const int l15  = lane & 15;
    const int lg   = lane >> 4;
    const int swz  = l15 & 7;

    const int m0 = blockIdx.x * 256;
    const int n0 = blockIdx.y * 256;

    f32x4 acc[8][4];
    {   f32x4 z4 = {0.f, 0.f, 0.f, 0.f};
#pragma unroll
        for (int i = 0; i < 8; ++i)
#pragma unroll
            for (int j = 0; j < 4; ++j) acc[i][j] = z4;
    }

    const int r0 = t >> 3,        c80 = (t & 7) ^ (r0 & 7);
    const int r1 = (512 + t) >> 3, c81 = (t & 7) ^ (r1 & 7);
    const u16* gA0 = xh + (size_t)(m0 + r0) * KXH + c80 * 8;
    const u16* gA1 = xh + (size_t)(m0 + r1) * KXH + c81 * 8;
    const u16* gB0 = Wg + (size_t)(n0 + r0) * KXH + c80 * 8;
    const u16* gB1 = Wg + (size_t)(n0 + r1) * KXH + c81 * 8;
    u16* lw0 = lds + w * 512;

#define STAGE8(ab, h, tau) do {                                              \
        int tc_ = (tau) < NTG ? (tau) : NTG - 1;                             \
        int bo_ = ((tau) & 1) * 32768 + (ab) * 16384 + (h) * 8192;           \
        const u16* s0_ = ((ab) ? gB0 : gA0) + (size_t)(h) * 128 * KXH + tc_ * 64; \
        const u16* s1_ = ((ab) ? gB1 : gA1) + (size_t)(h) * 128 * KXH + tc_ * 64; \
        gload16(s0_, lw0 + bo_);                                             \
        gload16(s1_, lw0 + bo_ + 4096);                                      \
    } while (0)

    const int uK0  = (lg ^ swz) * 8;
    const int uK1  = ((4 + lg) ^ swz) * 8;
    const int aoff = (wm * 128 + l15) * 64;
    const int boff = (wn * 64 + l15) * 64;

#define RD_A8(a)                                                             \
    _Pragma("unroll") for (int mi = 0; mi < 4; ++mi) {                       \
        const u16* p_ = bufA + aoff + ((a) * 64 + mi * 16) * 64;             \
        av[mi][0] = *(const s16x8*)(p_ + uK0);                               \
        av[mi][1] = *(const s16x8*)(p_ + uK1);                               \
    }
#define RD_B8(b, bvv)                                                        \
    _Pragma("unroll") for (int ni = 0; ni < 2; ++ni) {                       \
        const u16* p_ = bufB + boff + ((b) * 32 + ni * 16) * 64;             \
        bvv[ni][0] = *(const s16x8*)(p_ + uK0);                              \
        bvv[ni][1] = *(const s16x8*)(p_ + uK1);                              \
    }
#define MFMA_Q8(ar, bc, bvv)                                                 \
    __builtin_amdgcn_s_setprio(1);                                           \
    _Pragma("unroll") for (int mi = 0; mi < 4; ++mi)                         \
    _Pragma("unroll") for (int ni = 0; ni < 2; ++ni) {                       \
        acc[(ar) + mi][(bc) + ni] = __builtin_amdgcn_mfma_f32_16x16x32_bf16( \
            av[mi][0], bvv[ni][0], acc[(ar) + mi][(bc) + ni], 0, 0, 0);      \
        acc[(ar) + mi][(bc) + ni] = __builtin_amdgcn_mfma_f32_16x16x32_bf16( \
            av[mi][1], bvv[ni][1], acc[(ar) + mi][(bc) + ni], 0, 0, 0);      \
    }                                                                        \
    __builtin_amdgcn_s_setprio(0);

    // ---- prologue ----
    STAGE8(0, 0, 0); STAGE8(0, 1, 0); STAGE8(1, 0, 0); STAGE8(1, 1, 0);
    STAGE8(1, 0, 1); STAGE8(0, 0, 1);
    asm volatile("s_waitcnt vmcnt(4)" ::: "memory");
    __builtin_amdgcn_s_barrier();
    asm volatile("" ::: "memory");

    // ---- main loop ----
    for (int tt = 0; tt < NTG; ++tt) {
        const u16* bufA = lds + (tt & 1) * 32768;
        const u16* bufB = bufA + 16384;
        s16x8 av[4][2], bv0[2][2], bv1[2][2];
        RD_A8(0); RD_B8(0, bv0);
        STAGE8(0, 1, tt + 1);
        barrier_();
        MFMA_Q8(0, 0, bv0);
        barrier_();
        RD_B8(1, bv1);
        STAGE8(1, 1, tt + 1);
        barrier_();
        MFMA_Q8(0, 2, bv1);
        barrier_();
        RD_A8(1);
        STAGE8(1, 0, tt + 2);
        barrier_();
        MFMA_Q8(4, 0, bv0);
        barrier_();
        STAGE8(0, 0, tt + 2);
        barrier_();
        MFMA_Q8(4, 2, bv1);
        asm volatile("s_waitcnt vmcnt(4)" ::: "memory");
        barrier_();
    }

    // ---- fused LSTM epilogue ----
    const int hb = ((n0 + wn * 64) >> 6) * 16 + l15;
    const int cb = n0 + wn * 64 + l15;
    const float bi = bsum[cb];
    const float bf = bsum[cb + 16];
    const float bg = bsum[cb + 32];
    const float bo = bsum[cb + 48];
#pragma unroll
    for (int mb = 0; mb < 8; ++mb) {
#pragma unroll
        for (int r = 0; r < 4; ++r) {
            const int m = m0 + wm * 128 + mb * 16 + lg * 4 + r;
            const size_t idx = (size_t)m * DH + hb;
            float iv = acc[mb][0][r] + bi;
            float fv = acc[mb][1][r] + bf;
            float gv = acc[mb][2][r] + bg;
            float ov = acc[mb][3][r] + bo;
            float cn = sigmoid_(fv) * cin[idx] + sigmoid_(iv) * tanh_(gv);
            outc[idx] = cn;
            htl[idx] = f2bf(sigmoid_(ov) * tanh_(cn));
        }
        __builtin_amdgcn_sched_barrier(0);
    }
#undef STAGE8
#undef RD_A8
#undef RD_B8
#undef MFMA_Q8
}

// ---------------- m97-structure GEMM core (R1-verified) ------
template<int KTOT, int BM, int BN>
__device__ __forceinline__ void gemm_tile(
    const u16* __restrict__ A, int lda,
    const u16* __restrict__ Bw, int ldb,
    int m0, int n0, u16* As, u16* Bs,
    f32x4 (&acc)[BM / 32][BN / 32])
{
    constexpr int MI = BM / 32, NI = BN / 32;
    const int t    = threadIdx.x;
    const int lane = t & 63;
    const int w    = t >> 6;
    const int wrr  = (w >> 1) * (BM / 2);
    const int wcc  = (w & 1) * (BN / 2);

    const int rr  = t >> 3;
    const int sc8 = (t & 7) ^ (rr & 7);
    const u16* gA = A  + (size_t)(m0 + rr) * lda + sc8 * 8;
    const u16* gB = Bw + (size_t)(n0 + rr) * ldb + sc8 * 8;
    u16* lA = As + w * 512;
    u16* lB = Bs + w * 512;

    const int l15 = lane & 15;
    const int lg  = lane >> 4;
    const int swz = l15 & 7;
    const char* cA = (const char*)As;
    const char* cB = (const char*)Bs;
    const int roA = (wrr + l15) * 128;
    const int roB = (wcc + l15) * 128;
    const int c0  = ((0 + lg) ^ swz) * 16;
    const int c1  = ((4 + lg) ^ swz) * 16;

    for (int kt = 0; kt < KTOT; kt += 64) {
#pragma unroll
        for (int q = 0; q < BM / 32; ++q)
            gload16(gA + (size_t)q * 32 * lda, lA + q * 2048);
#pragma unroll
        for (int q = 0; q < BN / 32; ++q)
            gload16(gB + (size_t)q * 32 * ldb, lB + q * 2048);
        gA += 64; gB += 64;
        __syncthreads();

#pragma unroll
        for (int ks = 0; ks < 2; ++ks) {
            const int cc = ks ? c1 : c0;
            s16x8 av[MI], bv[NI];
#pragma unroll
            for (int mi = 0; mi < MI; ++mi)
                av[mi] = *(const s16x8*)(cA + roA + mi * 2048 + cc);
#pragma unroll
            for (int ni = 0; ni < NI; ++ni)
                bv[ni] = *(const s16x8*)(cB + roB + ni * 2048 + cc);
#pragma unroll
            for (int mi = 0; mi < MI; ++mi)
#pragma unroll
                for (int ni = 0; ni < NI; ++ni)
                    acc[mi][ni] = __builtin_amdgcn_mfma_f32_16x16x32_bf16(
                        av[mi], bv[ni], acc[mi][ni], 0, 0, 0);
        }
        __syncthreads();
    }
}

#define GEMM_PROLOGUE(BM, BN)                                      \
    __shared__ u16 As[(BM) * 64], Bs[(BN) * 64];                   \
    f32x4 acc[(BM) / 32][(BN) / 32];                               \
    {   f32x4 z4 = {0.f, 0.f, 0.f, 0.f};                           \
        _Pragma("unroll") for (int i = 0; i < (BM) / 32; ++i)      \
        _Pragma("unroll") for (int j = 0; j < (BN) / 32; ++j)      \
            acc[i][j] = z4; }                                      \
    const int m0 = blockIdx.x * (BM), n0 = blockIdx.y * (BN);      \
    const int lane = threadIdx.x & 63, w = threadIdx.x >> 6;       \
    const int wrr = (w >> 1) * ((BM) / 2),                         \
              wcc = (w & 1) * ((BN) / 2);                          \
    const int l15 = lane & 15, lg = lane >> 4;

#define EPILOGUE_LOOP(MI, NI, BODY)                                \
    _Pragma("unroll") for (int mi = 0; mi < (MI); ++mi) {          \
    _Pragma("unroll") for (int ni = 0; ni < (NI); ++ni)            \
    _Pragma("unroll") for (int r = 0; r < 4; ++r) {                \
        const int m = m0 + wrr + mi * 16 + lg * 4 + r;             \
        const int n = n0 + wcc + ni * 16 + l15;                    \
        float v = acc[mi][ni][r];                                  \
        BODY                                                       \
    }                                                              \
    __builtin_amdgcn_sched_barrier(0); }

// ---------------- Wc = W1 @ W2 (small standalone GEMM) ----------------
__global__ __launch_bounds__(256) void k_wc(
    const u16* __restrict__ W1z, const u16* __restrict__ W2t, u16* __restrict__ wc)
{
    GEMM_PROLOGUE(64, 128);
    gemm_tile<DH, 64, 128>(W1z, DH, W2t, DH, m0, n0, As, Bs, acc);
    EPILOGUE_LOOP(2, 4, { wc[(size_t)m * DH + n] = f2bf(v); })
}

// ---------------- f_node: algebraic RK4 (R6 flow, 128^2 tiles) ----------------
__global__ __launch_bounds__(256) void k_gemm_u(
    const u16* __restrict__ htl, const u16* __restrict__ W1z,
    const float* __restrict__ cvA,
    u16* __restrict__ ubuf, u16* __restrict__ z1)
{
    GEMM_PROLOGUE(128, 128);
    gemm_tile<DH, 128, 128>(htl, DH, W1z, DH, m0, n0, As, Bs, acc);
    EPILOGUE_LOOP(4, 4, {
        size_t idx = (size_t)m * DH + n;
        ubuf[idx] = f2bf(v);
        z1[idx] = f2bf(tanh_(v + cvA[n]));
    })
}

template<int IS4>
__global__ __launch_bounds__(256) void k_gemm_s(
    const u16* __restrict__ zin, const u16* __restrict__ wc,
    const u16* __restrict__ ubuf, const float* __restrict__ cv,
    const float* __restrict__ t0p, const float* __restrict__ t1p, float alpha,
    u16* __restrict__ zout,
    const u16* __restrict__ z1, const u16* __restrict__ z2,
    u16* __restrict__ Sb)
{
    GEMM_PROLOGUE(128, 128);
    gemm_tile<DH, 128, 128>(zin, DH, wc, DH, m0, n0, As, Bs, acc);
    const float ad = alpha * (*t1p - *t0p);
    EPILOGUE_LOOP(4, 4, {
        size_t idx = (size_t)m * DH + n;
        float zz = tanh_(bf2f(ubuf[idx]) + ad * v + cv[n]);
        if (IS4) {
            Sb[idx] = f2bf(bf2f(z1[idx]) + 2.f * bf2f(z2[idx])
                           + 2.f * bf2f(zin[idx]) + zz);
        } else {
            zout[idx] = f2bf(zz);
        }
    })
}

__global__ __launch_bounds__(256) void k_gemm_h(
    const u16* __restrict__ Sb, const u16* __restrict__ W2b,
    const float* __restrict__ b2, const u16* __restrict__ htl,
    const float* __restrict__ t0p, const float* __restrict__ t1p,
    float* __restrict__ outh)
{
    GEMM_PROLOGUE(128, 128);
    gemm_tile<DH, 128, 128>(Sb, DH, W2b, DH, m0, n0, As, Bs, acc);
    const float dtv = *t1p - *t0p;
    EPILOGUE_LOOP(4, 4, {
        size_t idx = (size_t)m * DH + n;
        outh[idx] = bf2f(htl[idx]) + (dtv * (1.0f / 6.0f)) * (v + 6.0f * b2[n]);
    })
}

// ---------------- cv constants: one wave per output row (R9) ----------------
// Replaces the serial per-thread vvec loop (uncoalesced, latency-bound,
// ~10-15us hidden in prep). Lane l sums j = l, l+64, ... (coalesced along the
// contiguous W1 row), 6-step butterfly reduce, lane 0 writes cvA/cvB/cvC.
__global__ __launch_bounds__(256) void k_cv(
    const float* __restrict__ W1, const float* __restrict__ b1,
    const float* __restrict__ b2,
    const float* __restrict__ t0p, const float* __restrict__ t1p,
    float* __restrict__ cvA, float* __restrict__ cvB, float* __restrict__ cvC)
{
    const int n    = blockIdx.x * 4 + (threadIdx.x >> 6);   // one wave per row
    const int lane = threadIdx.x & 63;
    const float* r = W1 + (size_t)n * (DH + 1);
    float s = 0.f;
#pragma unroll
    for (int j = 0; j < DH; j += 64)
        s += r[j + lane] * b2[j + lane];
#pragma unroll
    for (int d = 32; d >= 1; d >>= 1)
        s += __shfl_xor(s, d, 64);
    if (lane == 0) {
        const float t0v = *t0p, t1v = *t1p;
        const float dtv = t1v - t0v, tmv = t0v + 0.5f * dtv;
        const float wtn = r[DH];
        const float b1n = b1[n];
        cvA[n] = b1n + t0v * wtn;
        cvB[n] = 0.5f * dtv * s + b1n + tmv * wtn;
        cvC[n] = dtv * s + b1n + t1v * wtn;
    }
}

// ---------------- merged prep kernel ----------------
#define NW   (D4H * (KXH / 8))
#define NBS  (D4H / 8)
#define NR1  (DH * (DH / 8))
#define NW2  (DH * (DH / 8))
#define NT2  (DH * (DH / 8))
#define NXH  (DB * (KXH / 8))
#define NPREP (NW + NBS + NR1 + NW2 + NT2 + NXH)

__global__ __launch_bounds__(256) void k_prep_all(
    const float* __restrict__ x, const float* __restrict__ h,
    const float* __restrict__ Wih, const float* __restrict__ Whh,
    const float* __restrict__ bih, const float* __restrict__ bhh,
    const float* __restrict__ W1, const float* __restrict__ W2,
    u16* __restrict__ Wg, float* __restrict__ bsum,
    u16* __restrict__ W1z, u16* __restrict__ W2b, u16* __restrict__ W2t,
    u16* __restrict__ xh)
{
    int idx = blockIdx.x * 256 + threadIdx.x;
    if (idx < NW) {                                     // gate-interleaved Wg
        int n  = idx / (KXH / 8);
        int k8 = idx - n * (KXH / 8);
        int ro = ((n >> 4) & 3) * DH + (n >> 6) * 16 + (n & 15);
        const float* s = (k8 < DI / 8) ? (Wih + (size_t)ro * DI + k8 * 8)
                                       : (Whh + (size_t)ro * DH + (k8 - DI / 8) * 8);
        f32x4 x0 = *(const f32x4*)s;
        f32x4 x1 = *(const f32x4*)(s + 4);
        u16x8 o;
#pragma unroll
        for (int e = 0; e < 4; ++e) { o[e] = f2bf(x0[e]); o[e + 4] = f2bf(x1[e]); }
        *(u16x8*)(Wg + (size_t)idx * 8) = o;
        return;
    }
    idx -= NW;
    if (idx < NBS) {                                    // permuted combined bias
#pragma unroll
        for (int e = 0; e < 8; ++e) {
            int n = idx * 8 + e;
            int ro = ((n >> 4) & 3) * DH + (n >> 6) * 16 + (n & 15);
            bsum[n] = bih[ro] + bhh[ro];
        }
        return;
    }
    idx -= NBS;
    if (idx < NR1) {                                    // W1 (first DH cols)
        int n = idx >> 7, k8 = idx & 127;
        const float* s = W1 + (size_t)n * (DH + 1) + k8 * 8;  // stride 1025
        u16x8 o;
#pragma unroll
        for (int e = 0; e < 8; ++e) o[e] = f2bf(s[e]);
        *(u16x8*)(W1z + (size_t)idx * 8) = o;
        return;
    }
    idx -= NR1;
    if (idx < NW2) {                                    // W2 (row-major bf16)
        const float* s = W2 + (size_t)idx * 8;
        f32x4 x0 = *(const f32x4*)s;
        f32x4 x1 = *(const f32x4*)(s + 4);
        u16x8 o;
#pragma unroll
        for (int e = 0; e < 4; ++e) { o[e] = f2bf(x0[e]); o[e + 4] = f2bf(x1[e]); }
        *(u16x8*)(W2b + (size_t)idx * 8) = o;
        return;
    }
    idx -= NW2;
    if (idx < NT2) {                                    // W2t[i][j] = W2[j][i]
        int i = idx >> 7, j8 = (idx & 127) * 8;
        u16x8 o;
#pragma unroll
        for (int e = 0; e < 8; ++e) o[e] = f2bf(W2[(size_t)(j8 + e) * DH + i]);
        *(u16x8*)(W2t + (size_t)i * DH + j8) = o;
        return;
    }
    idx -= NT2;
    if (idx < NXH) {                                    // xh concat
        int b  = idx / (KXH / 8);
        int k8 = idx - b * (KXH / 8);
        const float* s = (k8 < DI / 8) ? (x + (size_t)b * DI + k8 * 8)
                                       : (h + (size_t)b * DH + (k8 - DI / 8) * 8);
        f32x4 x0 = *(const f32x4*)s;
        f32x4 x1 = *(const f32x4*)(s + 4);
        u16x8 o;
#pragma unroll
        for (int e = 0; e < 4; ++e) { o[e] = f2bf(x0[e]); o[e + 4] = f2bf(x1[e]); }
        *(u16x8*)(xh + (size_t)idx * 8) = o;
    }
}

// ---------------- launch ----------------
extern "C" void kernel_launch(void* const* d_in, const int* in_sizes, int n_in,
                              void* d_out, int out_size, void* d_ws, size_t ws_size,
                              hipStream_t stream)
{
    (void)in_sizes; (void)n_in; (void)out_size;
    const float* x_t = (const float*)d_in[0];
    const float* hin = (const float*)d_in[1];
    const float* cin = (const float*)d_in[2];
    const float* t0p = (const float*)d_in[3];
    const float* t1p = (const float*)d_in[4];
    const float* Wih = (const float*)d_in[5];
    const float* Whh = (const float*)d_in[6];
    const float* bih = (const float*)d_in[7];
    const float* bhh = (const float*)d_in[8];
    const float* W1  = (const float*)d_in[9];
    const float* b1  = (const float*)d_in[10];
    const float* W2  = (const float*)d_in[11];
    const float* b2  = (const float*)d_in[12];

    char* ws = (char*)d_ws;
    size_t off = 0;
    u16*   Wg    = (u16*)(ws + off);  off += (size_t)D4H * KXH * 2;  // 10.5 MB
    u16*   W1z   = (u16*)(ws + off);  off += (size_t)DH * DH * 2;
    u16*   W2b   = (u16*)(ws + off);  off += (size_t)DH * DH * 2;
    u16*   W2t   = (u16*)(ws + off);  off += (size_t)DH * DH * 2;
    u16*   wc    = (u16*)(ws + off);  off += (size_t)DH * DH * 2;
    float* bsum  = (float*)(ws + off); off += (size_t)D4H * 4;
    float* cvA   = (float*)(ws + off); off += (size_t)DH * 4;
    float* cvB   = (float*)(ws + off); off += (size_t)DH * 4;
    float* cvC   = (float*)(ws + off); off += (size_t)DH * 4;
    u16*   xh    = (u16*)(ws + off);  off += (size_t)DB * KXH * 2;   // 21.0 MB
    u16*   htl   = (u16*)(ws + off);  off += (size_t)DB * DH * 2;    // 16.8 MB
    u16*   ubuf  = (u16*)(ws + off);  off += (size_t)DB * DH * 2;
    u16*   z1    = (u16*)(ws + off);  off += (size_t)DB * DH * 2;
    u16*   z2    = (u16*)(ws + off);  off += (size_t)DB * DH * 2;
    u16*   z3    = (u16*)(ws + off);  off += (size_t)DB * DH * 2;
    u16*   Sb    = (u16*)(ws + off);  off += (size_t)DB * DH * 2;
    if (ws_size < off) return;  // insufficient workspace: fail validation cleanly

    float* outh = (float*)d_out;
    float* outc = outh + (size_t)DB * DH;

    k_cv<<<DH / 4, 256, 0, stream>>>(W1, b1, b2, t0p, t1p, cvA, cvB, cvC);

    k_prep_all<<<(NPREP + 255) / 256, 256, 0, stream>>>(
        x_t, hin, Wih, Whh, bih, bhh, W1, W2,
        Wg, bsum, W1z, W2b, W2t, xh);

    k_wc<<<dim3(DH / 64, DH / 128), 256, 0, stream>>>(W1z, W2t, wc);

    k_gates8<<<dim3(DB / 256, D4H / 256), 512, 0, stream>>>(
        xh, Wg, bsum, cin, outc, htl);

    dim3 gf(DB / 128, DH / 128);
    k_gemm_u<<<gf, 256, 0, stream>>>(htl, W1z, cvA, ubuf, z1);
    k_gemm_s<0><<<gf, 256, 0, stream>>>(z1, wc, ubuf, cvB, t0p, t1p, 0.5f,
                                        z2, nullptr, nullptr, nullptr);
    k_gemm_s<0><<<gf, 256, 0, stream>>>(z2, wc, ubuf, cvB, t0p, t1p, 0.5f,
                                        z3, nullptr, nullptr, nullptr);
    k_gemm_s<1><<<gf, 256, 0, stream>>>(z3, wc, ubuf, cvC, t0p, t1p, 1.0f,
                                        nullptr, z1, z2, Sb);
    k_gemm_h<<<gf, 256, 0, stream>>>(Sb, W2b, b2, htl, t0p, t1p, outh);
}